// Round 1
// baseline (332.495 us; speedup 1.0000x reference)
//
#include <hip/hip_runtime.h>
#include <cmath>

// Noisy quantum layer: density-matrix sim, 8 qubits, batch 32, depth 6.
// State: rho[sample][r][c] complex64 in d_ws (32 x 65536 cplx = 16 MB).
// Qubit q <-> bit (7-q) of r/c (qubit 0 = MSB, PennyLane ordering).
// All gates+noise fused into superoperators:
//   1q channel chain (amp,phase,depol) = real sparse 4x4 {A,B,C,D,E}
//   layer 1q op = N1 * Srz * Sry  (dense complex 4x4, precomputed per (l,q))
//   CNOT+noise  = bit-xor permutation then sparse N2 on each wire pair
// Encode collapses to a product state (computed directly per element).
// Assumes ws_size >= 16 MB + 16 KB.

typedef float2 cplx;

#define NQ     8
#define DIM    256
#define NELEM  65536
#define BATCH  32
#define DEPTH  6

__device__ __forceinline__ cplx cmul(cplx a, cplx b){
  return make_float2(a.x*b.x - a.y*b.y, a.x*b.y + a.y*b.x);
}
__device__ __forceinline__ cplx cadd(cplx a, cplx b){ return make_float2(a.x+b.x, a.y+b.y); }
__device__ __forceinline__ cplx cscale(float s, cplx a){ return make_float2(s*a.x, s*a.y); }

// 1q noise chain superop coefficients (real):
//   out00 = A*in00 + B*in11 ; out01 = C*in01 ; out10 = C*in10 ; out11 = D*in00 + E*in11
struct N1C { float A,B,C,D,E; };
__device__ __forceinline__ N1C noise_coeffs(float g){
  float ga = g*0.3f, gp = g*0.2f, p = g*0.5f;
  N1C n;
  n.A = 1.0f - 2.0f*p/3.0f;
  n.D = 2.0f*p/3.0f;
  n.B = ga*n.A + n.D*(1.0f-ga);
  n.E = n.D*ga + n.A*(1.0f-ga);
  n.C = (1.0f - 4.0f*p/3.0f) * sqrtf(1.0f-ga) * sqrtf(1.0f-gp);
  return n;
}

// insert a 0 bit at position p (shifting higher bits up)
__device__ __forceinline__ int ins0(int x, int p){
  int low = x & ((1<<p)-1);
  return ((x>>p)<<(p+1)) | low;
}

// ---------------- prep: per-(layer,qubit) 1q superops + encode 2x2s ----------------
__global__ __launch_bounds__(256) void prep_kernel(const float* __restrict__ x,
                                                   const float* __restrict__ w,
                                                   cplx* __restrict__ S1,
                                                   float* __restrict__ m){
  int t = threadIdx.x;
  N1C n1 = noise_coeffs(0.0003f);
  if (t < DEPTH*NQ){
    int l = t >> 3, i = t & 7;
    float w0 = w[(l*NQ+i)*2 + 0];
    float w1 = w[(l*NQ+i)*2 + 1];
    float c = cosf(0.5f*w0), s = sinf(0.5f*w0);
    float U[2][2] = {{c,-s},{s,c}};
    cplx ph01 = make_float2(cosf(w1), -sinf(w1));   // e^{-i w1}
    cplx ph10 = make_float2(ph01.x, -ph01.y);       // e^{+i w1}
    cplx* S = S1 + t*16;
    #pragma unroll
    for (int a=0;a<2;a++)
      #pragma unroll
      for (int b=0;b<2;b++){
        int k = 2*a+b;
        float u0a=U[0][a], u0b=U[0][b], u1a=U[1][a], u1b=U[1][b];
        S[0*4+k] = make_float2(n1.A*u0a*u0b + n1.B*u1a*u1b, 0.f);
        S[1*4+k] = cscale(n1.C*u0a*u1b, ph01);
        S[2*4+k] = cscale(n1.C*u1a*u0b, ph10);
        S[3*4+k] = make_float2(n1.D*u0a*u0b + n1.E*u1a*u1b, 0.f);
      }
  }
  // encode: rho_i = channel(RY(x)|0><0|RY^T) -> real 2x2, one per (sample,qubit)
  {
    int b = t >> 3, i = t & 7;
    float xv = x[b*NQ+i];
    float c = cosf(0.5f*xv), s = sinf(0.5f*xv);
    float p00=c*c, p01=c*s, p11=s*s;
    float* mm = m + t*4;
    mm[0] = n1.A*p00 + n1.B*p11;   // (0,0)
    mm[1] = n1.C*p01;              // (0,1)
    mm[2] = n1.C*p01;              // (1,0)
    mm[3] = n1.D*p00 + n1.E*p11;   // (1,1)
  }
}

// ---------------- init: rho = product of per-qubit 2x2s ----------------
__global__ __launch_bounds__(256) void init_kernel(const float* __restrict__ m,
                                                   cplx* __restrict__ rho){
  __shared__ float mm[32];
  int b = blockIdx.x >> 8;                       // 256 blocks per sample
  int e = ((blockIdx.x & 255) << 8) | threadIdx.x;
  if (threadIdx.x < 32) mm[threadIdx.x] = m[b*32 + threadIdx.x];
  __syncthreads();
  int r = e >> 8, c = e & 255;
  float v = 1.f;
  #pragma unroll
  for (int q=0;q<NQ;q++){
    int rq = (r >> (7-q)) & 1;
    int cq = (c >> (7-q)) & 1;
    v *= mm[q*4 + rq*2 + cq];
  }
  rho[(size_t)b*NELEM + e] = make_float2(v, 0.f);
}

// ---------------- layer pass: slab in LDS, fused CNOT+noise and rot+noise sops ----------------
// passB=0: local qubits 0..5 (L = (r>>2)*64 + (c>>2), outer = (r&3,c&3)):
//          CNOT(0,1)..CNOT(4,5) + rotations on qubits 0..4
// passB=1: local qubits 2..7 (L = (r&63)*64 + (c&63), outer = (r>>6,c>>6)):
//          CNOT(5,6),CNOT(6,7) + rotations on qubits 5..7
__global__ __launch_bounds__(256) void layer_kernel(cplx* __restrict__ rho,
                                                    const cplx* __restrict__ S1all,
                                                    int layer, int passB){
  __shared__ cplx slab[4096];
  __shared__ cplx sm[128];
  int t = threadIdx.x;
  int sample = blockIdx.x >> 4;
  int outer  = blockIdx.x & 15;
  int ro = outer >> 2, co = outer & 3;
  const cplx* Sl = S1all + layer*128;
  if (t < 128) sm[t] = Sl[t];
  cplx* g = rho + (size_t)sample * NELEM;

  #pragma unroll
  for (int k=0;k<16;k++){
    int L = (k<<8) | t;
    int rl = L >> 6, cl = L & 63;
    int addr = passB ? ((((ro<<6)|rl)<<8) | ((co<<6)|cl))
                     : ((((rl<<2)|ro)<<8) | ((cl<<2)|co));
    slab[L] = g[addr];
  }
  __syncthreads();

  N1C n2 = noise_coeffs(0.0065f);

  int pstart = passB ? 5 : 0;
  int pend   = passB ? 7 : 5;
  for (int p=pstart; p<pend; p++){
    int u = passB ? (7-p) : (5-p);   // control qubit bit in rloc/cloc
    int v = u - 1;                   // target qubit bit
    // free L-bit positions (ascending): v, v+1, 6+v, 7+v
    int base = ins0(ins0(ins0(ins0(t, v), v+1), 6+v), 7+v);
    cplx h[16];
    // gather with CNOT permutation folded in: h(ap,aq,bp,bq) = slab(ap, aq^ap, bp, bq^bp)
    #pragma unroll
    for (int idx=0; idx<16; idx++){
      int ap=(idx>>3)&1, aq=(idx>>2)&1, bp=(idx>>1)&1, bq=idx&1;
      int pos = base | (ap<<(6+u)) | ((aq^ap)<<(6+v)) | (bp<<u) | ((bq^bp)<<v);
      h[idx] = slab[pos];
    }
    // noise on wire p: pairs (ap,bp), idx bits 3 and 1
    #pragma unroll
    for (int aq=0;aq<2;aq++)
      #pragma unroll
      for (int bq=0;bq<2;bq++){
        int i00 = (aq<<2)|bq;
        cplx t00=h[i00], t01=h[i00|2], t10=h[i00|8], t11=h[i00|10];
        h[i00]    = cadd(cscale(n2.A,t00), cscale(n2.B,t11));
        h[i00|2]  = cscale(n2.C, t01);
        h[i00|8]  = cscale(n2.C, t10);
        h[i00|10] = cadd(cscale(n2.D,t00), cscale(n2.E,t11));
      }
    // noise on wire p+1: pairs (aq,bq), idx bits 2 and 0
    #pragma unroll
    for (int ap=0;ap<2;ap++)
      #pragma unroll
      for (int bp=0;bp<2;bp++){
        int i00 = (ap<<3)|(bp<<1);
        cplx t00=h[i00], t01=h[i00|1], t10=h[i00|4], t11=h[i00|5];
        h[i00]   = cadd(cscale(n2.A,t00), cscale(n2.B,t11));
        h[i00|1] = cscale(n2.C, t01);
        h[i00|4] = cscale(n2.C, t10);
        h[i00|5] = cadd(cscale(n2.D,t00), cscale(n2.E,t11));
      }
    // scatter back (unpermuted positions)
    #pragma unroll
    for (int idx=0; idx<16; idx++){
      int ap=(idx>>3)&1, aq=(idx>>2)&1, bp=(idx>>1)&1, bq=idx&1;
      int pos = base | (ap<<(6+u)) | (aq<<(6+v)) | (bp<<u) | (bq<<v);
      slab[pos] = h[idx];
    }
    __syncthreads();
  }

  int qstart = passB ? 5 : 0;
  int qend   = passB ? 8 : 5;
  for (int q=qstart; q<qend; q++){
    int u = passB ? (7-q) : (5-q);
    const cplx* S = sm + q*16;
    #pragma unroll
    for (int gi=0; gi<4; gi++){
      int gid = (gi<<8) | t;                    // 1024 groups total
      int base = ins0(ins0(gid, u), 6+u);
      int pa = base | (1<<(6+u));
      cplx v0 = slab[base];                     // (a,b)=(0,0)
      cplx v1 = slab[base | (1<<u)];            // (0,1)
      cplx v2 = slab[pa];                       // (1,0)
      cplx v3 = slab[pa | (1<<u)];              // (1,1)
      cplx o0 = cadd(cadd(cmul(S[0],v0),  cmul(S[1],v1)),  cadd(cmul(S[2],v2),  cmul(S[3],v3)));
      cplx o1 = cadd(cadd(cmul(S[4],v0),  cmul(S[5],v1)),  cadd(cmul(S[6],v2),  cmul(S[7],v3)));
      cplx o2 = cadd(cadd(cmul(S[8],v0),  cmul(S[9],v1)),  cadd(cmul(S[10],v2), cmul(S[11],v3)));
      cplx o3 = cadd(cadd(cmul(S[12],v0), cmul(S[13],v1)), cadd(cmul(S[14],v2), cmul(S[15],v3)));
      slab[base]             = o0;
      slab[base | (1<<u)]    = o1;
      slab[pa]               = o2;
      slab[pa | (1<<u)]      = o3;
    }
    __syncthreads();
  }

  #pragma unroll
  for (int k=0;k<16;k++){
    int L = (k<<8) | t;
    int rl = L >> 6, cl = L & 63;
    int addr = passB ? ((((ro<<6)|rl)<<8) | ((co<<6)|cl))
                     : ((((rl<<2)|ro)<<8) | ((cl<<2)|co));
    g[addr] = slab[L];
  }
}

// ---------------- expectation: sum_r sign(r) * Re rho[r][r] ----------------
__global__ __launch_bounds__(256) void expect_kernel(const cplx* __restrict__ rho,
                                                     float* __restrict__ out){
  __shared__ float ps[4];
  int b = blockIdx.x;
  int t = threadIdx.x;
  float v = rho[(size_t)b*NELEM + (size_t)t*257].x;
  v = (t < 128) ? v : -v;
  #pragma unroll
  for (int o=32;o>0;o>>=1) v += __shfl_down(v, o, 64);
  if ((t & 63) == 0) ps[t>>6] = v;
  __syncthreads();
  if (t == 0) out[b] = ps[0]+ps[1]+ps[2]+ps[3];
}

extern "C" void kernel_launch(void* const* d_in, const int* in_sizes, int n_in,
                              void* d_out, int out_size, void* d_ws, size_t ws_size,
                              hipStream_t stream) {
  const float* x = (const float*)d_in[0];   // [32,8]
  const float* w = (const float*)d_in[1];   // [6,8,2]
  float* out = (float*)d_out;               // [32,1] f32
  char* ws = (char*)d_ws;

  cplx*  rho = (cplx*)ws;                                     // 16 MB
  cplx*  S1  = (cplx*)(ws + (size_t)BATCH*NELEM*sizeof(cplx));// 768 cplx
  float* m   = (float*)(ws + (size_t)BATCH*NELEM*sizeof(cplx) + DEPTH*NQ*16*sizeof(cplx));

  prep_kernel<<<1, 256, 0, stream>>>(x, w, S1, m);
  init_kernel<<<BATCH*NELEM/256, 256, 0, stream>>>(m, rho);
  for (int l=0; l<DEPTH; l++){
    layer_kernel<<<BATCH*16, 256, 0, stream>>>(rho, S1, l, 0);
    layer_kernel<<<BATCH*16, 256, 0, stream>>>(rho, S1, l, 1);
  }
  expect_kernel<<<BATCH, 256, 0, stream>>>(rho, out);
}

// Round 2
// 185.110 us; speedup vs baseline: 1.7962x; 1.7962x over previous
//
#include <hip/hip_runtime.h>
#include <cmath>

// Noisy 8-qubit density-matrix sim, batch 32, depth 6 — 2-pass trapezoid version.
//
// Op stream per layer l: C(0,1)..C(6,7) (CNOT+2q noise), then R(0..7) (RY*RZ+1q noise).
// R(q) commutes with any op not touching qubit q  =>  fuse R(q) into stage
// T(q,l) = C(q,q+1)+noise2(q)+noise2(q+1)+R(q);  R(7) folded into T(6,l).
// Deps: T(q,l) needs T(q-1,l), T(q,l-1), T(q+1,l-1) -> 1D lightcone, slope 1/layer.
// With a 7-qubit local window (14 bits = 16384 cplx = 128 KB LDS):
//   pass1 window [0..6]: T(q,l) for q<=5-l  (21 stages) + init fused (product state)
//   pass2 window [1..7]: T(q,l) for q in [6-l..6] (21 stages) + expectation fused
// Global traffic: 16 MB write (pass1) + 16 MB read (pass2). Layout between passes:
//   gaddr = (r&1)<<15 | (c&1)<<14 | (r>>1)<<7 | (c>>1)   per sample.
// Qubit q <-> bit (7-q) of r/c (qubit 0 = MSB).

typedef float2 cplx;

#define NQ     8
#define NELEM  65536
#define BATCH  32
#define DEPTH  6

__device__ __forceinline__ cplx cmul(cplx a, cplx b){
  return make_float2(a.x*b.x - a.y*b.y, a.x*b.y + a.y*b.x);
}
__device__ __forceinline__ cplx cadd(cplx a, cplx b){ return make_float2(a.x+b.x, a.y+b.y); }
__device__ __forceinline__ cplx cscale(float s, cplx a){ return make_float2(s*a.x, s*a.y); }

// 1q noise chain (amp,phase,depol) as real sparse superop:
// out00=A*in00+B*in11; out01=C*in01; out10=C*in10; out11=D*in00+E*in11
struct N1C { float A,B,C,D,E; };
__device__ __forceinline__ N1C noise_coeffs(float g){
  float ga = g*0.3f, gp = g*0.2f, p = g*0.5f;
  N1C n;
  n.A = 1.0f - 2.0f*p/3.0f;
  n.D = 2.0f*p/3.0f;
  n.B = ga*n.A + n.D*(1.0f-ga);
  n.E = n.D*ga + n.A*(1.0f-ga);
  n.C = (1.0f - 4.0f*p/3.0f) * sqrtf(1.0f-ga) * sqrtf(1.0f-gp);
  return n;
}

__device__ __forceinline__ int ins0(int x, int p){
  int low = x & ((1<<p)-1);
  return ((x>>p)<<(p+1)) | low;
}

// ---------------- prep: per-(layer,qubit) 1q superops + encode 2x2s ----------------
__global__ __launch_bounds__(256) void prep_kernel(const float* __restrict__ x,
                                                   const float* __restrict__ w,
                                                   cplx* __restrict__ S1,
                                                   float* __restrict__ m){
  int t = threadIdx.x;
  N1C n1 = noise_coeffs(0.0003f);
  if (t < DEPTH*NQ){
    int l = t >> 3, i = t & 7;
    float w0 = w[(l*NQ+i)*2 + 0];
    float w1 = w[(l*NQ+i)*2 + 1];
    float c = cosf(0.5f*w0), s = sinf(0.5f*w0);
    float U[2][2] = {{c,-s},{s,c}};
    cplx ph01 = make_float2(cosf(w1), -sinf(w1));   // e^{-i w1}
    cplx ph10 = make_float2(ph01.x, -ph01.y);       // e^{+i w1}
    cplx* S = S1 + t*16;
    #pragma unroll
    for (int a=0;a<2;a++)
      #pragma unroll
      for (int b=0;b<2;b++){
        int k = 2*a+b;
        float u0a=U[0][a], u0b=U[0][b], u1a=U[1][a], u1b=U[1][b];
        S[0*4+k] = make_float2(n1.A*u0a*u0b + n1.B*u1a*u1b, 0.f);
        S[1*4+k] = cscale(n1.C*u0a*u1b, ph01);
        S[2*4+k] = cscale(n1.C*u1a*u0b, ph10);
        S[3*4+k] = make_float2(n1.D*u0a*u0b + n1.E*u1a*u1b, 0.f);
      }
  }
  {
    int b = t >> 3, i = t & 7;
    float xv = x[b*NQ+i];
    float c = cosf(0.5f*xv), s = sinf(0.5f*xv);
    float p00=c*c, p01=c*s, p11=s*s;
    float* mm = m + t*4;
    mm[0] = n1.A*p00 + n1.B*p11;
    mm[1] = n1.C*p01;
    mm[2] = n1.C*p01;
    mm[3] = n1.D*p00 + n1.E*p11;
  }
}

// ---------------- fused stage: CNOT(u,u-1)+noise2 pair + R(control) [+ R(target)] ----------------
// Slab L (14 bits): row-local bits 7..13, col-local bits 0..6.
// Control qubit at row bit 7+u / col bit u; target at 6+u / u-1.  u in [1..6].
// h idx = a<<3 | b<<2 | cc<<1 | d  (a=row-ctl, b=row-tgt, cc=col-ctl, d=col-tgt)
__device__ __forceinline__ void do_stage(cplx* slab, const cplx* __restrict__ S,
                                         const cplx* __restrict__ S7, int u, int t){
  N1C n2 = noise_coeffs(0.0065f);
  int base = ins0(ins0(ins0(ins0(t, u-1), u), 6+u), 7+u);
  int ru1 = 1<<(7+u), ru0 = 1<<(6+u), cu1 = 1<<u, cu0 = 1<<(u-1);
  cplx h[16];
  // gather with CNOT permutation folded in
  #pragma unroll
  for (int idx=0; idx<16; idx++){
    int a=(idx>>3)&1, b=(idx>>2)&1, cc=(idx>>1)&1, d=idx&1;
    int pos = base + a*ru1 + (b^a)*ru0 + cc*cu1 + (d^cc)*cu0;
    h[idx] = slab[pos];
  }
  // noise2 on control wire: (a,cc) = idx bits 3,1
  #pragma unroll
  for (int b=0;b<2;b++)
    #pragma unroll
    for (int d=0;d<2;d++){
      int i00 = (b<<2)|d;
      cplx t00=h[i00], t01=h[i00|2], t10=h[i00|8], t11=h[i00|10];
      h[i00]    = cadd(cscale(n2.A,t00), cscale(n2.B,t11));
      h[i00|2]  = cscale(n2.C, t01);
      h[i00|8]  = cscale(n2.C, t10);
      h[i00|10] = cadd(cscale(n2.D,t00), cscale(n2.E,t11));
    }
  // noise2 on target wire: (b,d) = idx bits 2,0
  #pragma unroll
  for (int a=0;a<2;a++)
    #pragma unroll
    for (int cc=0;cc<2;cc++){
      int i00 = (a<<3)|(cc<<1);
      cplx t00=h[i00], t01=h[i00|1], t10=h[i00|4], t11=h[i00|5];
      h[i00]   = cadd(cscale(n2.A,t00), cscale(n2.B,t11));
      h[i00|1] = cscale(n2.C, t01);
      h[i00|4] = cscale(n2.C, t10);
      h[i00|5] = cadd(cscale(n2.D,t00), cscale(n2.E,t11));
    }
  // R(control): dense 4x4 on (a,cc), k = 2a+cc
  #pragma unroll
  for (int b=0;b<2;b++)
    #pragma unroll
    for (int d=0;d<2;d++){
      int i0 = (b<<2)|d;
      cplx v0=h[i0], v1=h[i0|2], v2=h[i0|8], v3=h[i0|10];
      h[i0]    = cadd(cadd(cmul(S[0],v0),  cmul(S[1],v1)),  cadd(cmul(S[2],v2),  cmul(S[3],v3)));
      h[i0|2]  = cadd(cadd(cmul(S[4],v0),  cmul(S[5],v1)),  cadd(cmul(S[6],v2),  cmul(S[7],v3)));
      h[i0|8]  = cadd(cadd(cmul(S[8],v0),  cmul(S[9],v1)),  cadd(cmul(S[10],v2), cmul(S[11],v3)));
      h[i0|10] = cadd(cadd(cmul(S[12],v0), cmul(S[13],v1)), cadd(cmul(S[14],v2), cmul(S[15],v3)));
    }
  // optional R(target) (only for T(6,l): R(7)), k = 2b+d
  if (S7){
    #pragma unroll
    for (int a=0;a<2;a++)
      #pragma unroll
      for (int cc=0;cc<2;cc++){
        int i0 = (a<<3)|(cc<<1);
        cplx v0=h[i0], v1=h[i0|1], v2=h[i0|4], v3=h[i0|5];
        h[i0]   = cadd(cadd(cmul(S7[0],v0),  cmul(S7[1],v1)),  cadd(cmul(S7[2],v2),  cmul(S7[3],v3)));
        h[i0|1] = cadd(cadd(cmul(S7[4],v0),  cmul(S7[5],v1)),  cadd(cmul(S7[6],v2),  cmul(S7[7],v3)));
        h[i0|4] = cadd(cadd(cmul(S7[8],v0),  cmul(S7[9],v1)),  cadd(cmul(S7[10],v2), cmul(S7[11],v3)));
        h[i0|5] = cadd(cadd(cmul(S7[12],v0), cmul(S7[13],v1)), cadd(cmul(S7[14],v2), cmul(S7[15],v3)));
      }
  }
  // scatter (unpermuted)
  #pragma unroll
  for (int idx=0; idx<16; idx++){
    int a=(idx>>3)&1, b=(idx>>2)&1, cc=(idx>>1)&1, d=idx&1;
    int pos = base + a*ru1 + b*ru0 + cc*cu1 + d*cu0;
    slab[pos] = h[idx];
  }
}

// ---------------- pass 1: window qubits 0..6, outer = qubit 7 bits (r0,c0) ----------------
__global__ __launch_bounds__(1024) void pass1_kernel(cplx* __restrict__ rho,
                                                     const cplx* __restrict__ S1,
                                                     const float* __restrict__ m){
  __shared__ cplx slab[16384];
  __shared__ float sm_m[32];
  int t = threadIdx.x;
  int b = blockIdx.x >> 2, o = blockIdx.x & 3;
  int r0 = o >> 1, c0 = o & 1;
  if (t < 32) sm_m[t] = m[b*32 + t];
  __syncthreads();
  float m7 = sm_m[7*4 + r0*2 + c0];
  // init: product state (encode already folded into m)
  #pragma unroll
  for (int k=0;k<16;k++){
    int L = (k<<10) | t;
    int rl = L >> 7, cl = L & 127;
    float v = m7;
    #pragma unroll
    for (int i=0;i<7;i++)
      v *= sm_m[i*4 + ((rl>>(6-i))&1)*2 + ((cl>>(6-i))&1)];
    slab[L] = make_float2(v, 0.f);
  }
  __syncthreads();
  // trapezoid: T(q,l) for q <= 5-l ; qubit q -> u = 6-q
  for (int l=0;l<DEPTH;l++){
    for (int q=0; q<=5-l; q++){
      do_stage(slab, S1 + (l*8+q)*16, nullptr, 6-q, t);
      __syncthreads();
    }
  }
  cplx* g = rho + (size_t)b*NELEM + (o<<14);
  #pragma unroll
  for (int k=0;k<16;k++){
    int L = (k<<10) | t;
    g[L] = slab[L];
  }
}

// ---------------- pass 2: window qubits 1..7, outer = qubit 0 bits (r7,c7) ----------------
__global__ __launch_bounds__(1024) void pass2_kernel(const cplx* __restrict__ rho,
                                                     const cplx* __restrict__ S1,
                                                     float* __restrict__ partial){
  __shared__ cplx slab[16384];
  __shared__ float red[2];
  int t = threadIdx.x;
  int b = blockIdx.x >> 2, o = blockIdx.x & 3;
  int r7 = o >> 1, c7 = o & 1;
  const cplx* g = rho + (size_t)b*NELEM;
  #pragma unroll
  for (int k=0;k<16;k++){
    int L = (k<<10) | t;
    int rl = L >> 7, cl = L & 127;
    int gaddr = ((rl&1)<<15) | ((cl&1)<<14) | (((r7<<6)|(rl>>1))<<7) | ((c7<<6)|(cl>>1));
    slab[L] = g[gaddr];
  }
  __syncthreads();
  // trapezoid: T(q,l) for q in [6-l .. 6] ; qubit q -> u = 7-q ; T(6,l) also applies R(7)
  for (int l=0;l<DEPTH;l++){
    for (int q=6-l; q<=6; q++){
      do_stage(slab, S1 + (l*8+q)*16, (q==6) ? (S1 + (l*8+7)*16) : nullptr, 7-q, t);
      __syncthreads();
    }
  }
  // fused expectation: diag needs r7==c7 and rl==cl; sign from qubit0 = r7
  if (r7 == c7){
    float v = 0.f;
    if (t < 128){
      v = slab[t*129].x;
      #pragma unroll
      for (int s=32;s>0;s>>=1) v += __shfl_down(v, s, 64);
      if ((t & 63) == 0) red[t>>6] = v;
    }
    __syncthreads();
    if (t == 0){
      float s = red[0] + red[1];
      partial[b*2 + r7] = r7 ? -s : s;
    }
  }
}

// ---------------- final: out[b] = partial[2b] + partial[2b+1] ----------------
__global__ void final_kernel(const float* __restrict__ partial, float* __restrict__ out){
  int t = threadIdx.x;
  if (t < BATCH) out[t] = partial[2*t] + partial[2*t+1];
}

extern "C" void kernel_launch(void* const* d_in, const int* in_sizes, int n_in,
                              void* d_out, int out_size, void* d_ws, size_t ws_size,
                              hipStream_t stream) {
  const float* x = (const float*)d_in[0];   // [32,8]
  const float* w = (const float*)d_in[1];   // [6,8,2]
  float* out = (float*)d_out;               // [32,1] f32
  char* ws = (char*)d_ws;

  cplx*  rho     = (cplx*)ws;                                   // 16 MB
  cplx*  S1      = (cplx*)(ws + (size_t)16777216);              // 48*16 cplx = 6 KB
  float* m       = (float*)(ws + (size_t)16777216 + 6144);      // 1024 f = 4 KB
  float* partial = (float*)(ws + (size_t)16777216 + 6144 + 4096);

  prep_kernel<<<1, 256, 0, stream>>>(x, w, S1, m);
  pass1_kernel<<<BATCH*4, 1024, 0, stream>>>(rho, S1, m);
  pass2_kernel<<<BATCH*4, 1024, 0, stream>>>(rho, S1, partial);
  final_kernel<<<1, 64, 0, stream>>>(partial, out);
}

// Round 3
// 134.480 us; speedup vs baseline: 2.4724x; 1.3765x over previous
//
#include <hip/hip_runtime.h>
#include <cmath>

// Noisy 8-qubit density-matrix sim, batch 32, depth 6 — 4-pass, 6-qubit-window version.
// Qubit q <-> bit (7-q) of r/c. Fused stages T(q,l) = CNOT(q,q+1)+noise2+R(q) (R7 folded
// into T(6,l)). Schedule: A win[q0..5] (outer bits 0,1): T(q,l) q<=4-l (15 stages, init fused);
// B win[q2..7] (outer bits 6,7): l0:q5,6 l1:q4..6 l2:q3..6 l3:q2..6 (14); C win[q0..5]:
// l4:q1..4 l5:q0..3 (8); D win[q2..7] diag-outer only: l4:q5,6 l5:q4..6 (5, expectation fused).
// Slab: 4096 cplx, L = rl*64+cl (6-bit row/col locals). LDS bank fix: phys = L ^ rot3(rl)
// + per-stage lane-bit placement tables (lane bits t0..t3 always control phys bank bits 0..3).
// Buffers ping-pong: A->buf0, B: buf0->buf1, C: buf1->buf0, D: buf0->partial.

typedef float2 cplx;

#define BATCH 32
#define DEPTH 6

__device__ __forceinline__ cplx cmul(cplx a, cplx b){
  return make_float2(a.x*b.x - a.y*b.y, a.x*b.y + a.y*b.x);
}
__device__ __forceinline__ cplx cadd(cplx a, cplx b){ return make_float2(a.x+b.x, a.y+b.y); }
__device__ __forceinline__ cplx cscale(float s, cplx a){ return make_float2(s*a.x, s*a.y); }

struct N1C { float A,B,C,D,E; };
__device__ __forceinline__ N1C noise_coeffs(float g){
  float ga = g*0.3f, gp = g*0.2f, p = g*0.5f;
  N1C n;
  n.A = 1.0f - 2.0f*p/3.0f;
  n.D = 2.0f*p/3.0f;
  n.B = ga*n.A + n.D*(1.0f-ga);
  n.E = n.D*ga + n.A*(1.0f-ga);
  n.C = (1.0f - 4.0f*p/3.0f) * sqrtf(1.0f-ga) * sqrtf(1.0f-gp);
  return n;
}

// swizzle: phys = L ^ rot-left-3(row-local)  (col bits XORed by rotated row bits)
__device__ __forceinline__ int physof(int L){
  int rl = L >> 6;
  int rot = ((rl<<3)|(rl>>3)) & 63;
  return L ^ rot;
}
// phys-space single-bit mask for logical position p
__device__ __forceinline__ constexpr int KPc(int p){
  return (p < 6) ? (1<<p) : ((1<<p) | (1 << (((p-6)+3)%6)));
}

// per-stage lane-bit -> free-logical-position tables (t0..t3 control phys banks 0..3)
template<int U>
__device__ __forceinline__ int base_for(int t){
  constexpr int P[6][8] = {
    {0,0,0,0,0,0,0,0},
    {9,10,2,3,4,5,8,11},   // u=1 (active {0,1,6,7})
    {0,10,11,3,4,5,6,9},   // u=2 (active {1,2,7,8})
    {0,1,11,6,4,5,7,10},   // u=3 (active {2,3,8,9})
    {0,1,2,6,5,7,8,11},    // u=4 (active {3,4,9,10})
    {0,1,2,3,7,8,6,9}};    // u=5 (active {4,5,10,11})
  int b = 0;
  #pragma unroll
  for (int i=0;i<8;i++) b ^= (-((t>>i)&1)) & KPc(P[U][i]);
  return b;
}

// ---------------- prep: per-(layer,qubit) 1q superops + encode 2x2s ----------------
__global__ __launch_bounds__(256) void prep_kernel(const float* __restrict__ x,
                                                   const float* __restrict__ w,
                                                   cplx* __restrict__ S1,
                                                   float* __restrict__ m){
  int t = threadIdx.x;
  N1C n1 = noise_coeffs(0.0003f);
  if (t < DEPTH*8){
    int l = t >> 3, i = t & 7;
    float w0 = w[(l*8+i)*2 + 0];
    float w1 = w[(l*8+i)*2 + 1];
    float c = cosf(0.5f*w0), s = sinf(0.5f*w0);
    float U[2][2] = {{c,-s},{s,c}};
    cplx ph01 = make_float2(cosf(w1), -sinf(w1));
    cplx ph10 = make_float2(ph01.x, -ph01.y);
    cplx* S = S1 + t*16;
    #pragma unroll
    for (int a=0;a<2;a++)
      #pragma unroll
      for (int b=0;b<2;b++){
        int k = 2*a+b;
        float u0a=U[0][a], u0b=U[0][b], u1a=U[1][a], u1b=U[1][b];
        S[0*4+k] = make_float2(n1.A*u0a*u0b + n1.B*u1a*u1b, 0.f);
        S[1*4+k] = cscale(n1.C*u0a*u1b, ph01);
        S[2*4+k] = cscale(n1.C*u1a*u0b, ph10);
        S[3*4+k] = make_float2(n1.D*u0a*u0b + n1.E*u1a*u1b, 0.f);
      }
  }
  {
    int b = t >> 3, i = t & 7;
    float xv = x[b*8+i];
    float c = cosf(0.5f*xv), s = sinf(0.5f*xv);
    float p00=c*c, p01=c*s, p11=s*s;
    float* mm = m + t*4;
    mm[0] = n1.A*p00 + n1.B*p11;
    mm[1] = n1.C*p01;
    mm[2] = n1.C*p01;
    mm[3] = n1.D*p00 + n1.E*p11;
  }
}

// ---------------- fused stage on 12-bit slab ----------------
// active logical bits: col {U-1,U}, row {5+U,6+U}; h idx = a<<3|b<<2|cc<<1|d
template<int U, bool R7>
__device__ __forceinline__ void do_stage(cplx* slab, const cplx* __restrict__ S,
                                         const cplx* __restrict__ S7, int bp, N1C n2){
  constexpr int KA = KPc(6+U), KB = KPc(5+U), KC = 1<<U, KD = 1<<(U-1);
  cplx h[16];
  #pragma unroll
  for (int idx=0; idx<16; idx++){
    int a=(idx>>3)&1, b=(idx>>2)&1, cc=(idx>>1)&1, d=idx&1;
    int pos = bp ^ (a*KA) ^ ((b^a)*KB) ^ (cc*KC) ^ ((d^cc)*KD);  // CNOT folded in
    h[idx] = slab[pos];
  }
  // noise2 on control wire: (a,cc) = bits 3,1
  #pragma unroll
  for (int b=0;b<2;b++)
    #pragma unroll
    for (int d=0;d<2;d++){
      int i00 = (b<<2)|d;
      cplx t00=h[i00], t01=h[i00|2], t10=h[i00|8], t11=h[i00|10];
      h[i00]    = cadd(cscale(n2.A,t00), cscale(n2.B,t11));
      h[i00|2]  = cscale(n2.C, t01);
      h[i00|8]  = cscale(n2.C, t10);
      h[i00|10] = cadd(cscale(n2.D,t00), cscale(n2.E,t11));
    }
  // noise2 on target wire: (b,d) = bits 2,0
  #pragma unroll
  for (int a=0;a<2;a++)
    #pragma unroll
    for (int cc=0;cc<2;cc++){
      int i00 = (a<<3)|(cc<<1);
      cplx t00=h[i00], t01=h[i00|1], t10=h[i00|4], t11=h[i00|5];
      h[i00]   = cadd(cscale(n2.A,t00), cscale(n2.B,t11));
      h[i00|1] = cscale(n2.C, t01);
      h[i00|4] = cscale(n2.C, t10);
      h[i00|5] = cadd(cscale(n2.D,t00), cscale(n2.E,t11));
    }
  // R(control): dense 4x4 on (a,cc), k = 2a+cc
  #pragma unroll
  for (int b=0;b<2;b++)
    #pragma unroll
    for (int d=0;d<2;d++){
      int i0 = (b<<2)|d;
      cplx v0=h[i0], v1=h[i0|2], v2=h[i0|8], v3=h[i0|10];
      h[i0]    = cadd(cadd(cmul(S[0],v0),  cmul(S[1],v1)),  cadd(cmul(S[2],v2),  cmul(S[3],v3)));
      h[i0|2]  = cadd(cadd(cmul(S[4],v0),  cmul(S[5],v1)),  cadd(cmul(S[6],v2),  cmul(S[7],v3)));
      h[i0|8]  = cadd(cadd(cmul(S[8],v0),  cmul(S[9],v1)),  cadd(cmul(S[10],v2), cmul(S[11],v3)));
      h[i0|10] = cadd(cadd(cmul(S[12],v0), cmul(S[13],v1)), cadd(cmul(S[14],v2), cmul(S[15],v3)));
    }
  if (R7){
    #pragma unroll
    for (int a=0;a<2;a++)
      #pragma unroll
      for (int cc=0;cc<2;cc++){
        int i0 = (a<<3)|(cc<<1);
        cplx v0=h[i0], v1=h[i0|1], v2=h[i0|4], v3=h[i0|5];
        h[i0]   = cadd(cadd(cmul(S7[0],v0),  cmul(S7[1],v1)),  cadd(cmul(S7[2],v2),  cmul(S7[3],v3)));
        h[i0|1] = cadd(cadd(cmul(S7[4],v0),  cmul(S7[5],v1)),  cadd(cmul(S7[6],v2),  cmul(S7[7],v3)));
        h[i0|4] = cadd(cadd(cmul(S7[8],v0),  cmul(S7[9],v1)),  cadd(cmul(S7[10],v2), cmul(S7[11],v3)));
        h[i0|5] = cadd(cadd(cmul(S7[12],v0), cmul(S7[13],v1)), cadd(cmul(S7[14],v2), cmul(S7[15],v3)));
      }
  }
  #pragma unroll
  for (int idx=0; idx<16; idx++){
    int a=(idx>>3)&1, b=(idx>>2)&1, cc=(idx>>1)&1, d=idx&1;
    int pos = bp ^ (a*KA) ^ (b*KB) ^ (cc*KC) ^ (d*KD);
    slab[pos] = h[idx];
  }
}

#define STG(l,q,u)  do_stage<u,false>(slab, sS+((l)*8+(q))*16, nullptr, base_for<u>(t), n2); __syncthreads();
#define STG7(l,q,u) do_stage<u,true >(slab, sS+((l)*8+(q))*16, sS+((l)*8+7)*16, base_for<u>(t), n2); __syncthreads();

// ---------------- pass A: window qubits 0..5 (bits 2..7), outer = bits 0,1 ----------------
__global__ __launch_bounds__(256) void passA_kernel(const cplx* __restrict__ S1,
                                                    const float* __restrict__ m,
                                                    cplx* __restrict__ gout){
  __shared__ cplx slab[4096];
  __shared__ cplx sS[768];
  __shared__ float sm[32];
  int t = threadIdx.x;
  int s = blockIdx.x >> 4, oA = blockIdx.x & 15;
  for (int i=t;i<768;i+=256) sS[i]=S1[i];
  if (t<32) sm[t]=m[s*32+t];
  __syncthreads();
  int oAr=oA>>2, oAc=oA&3;
  float m67 = sm[24+(oAr>>1)*2+(oAc>>1)] * sm[28+(oAr&1)*2+(oAc&1)];
  #pragma unroll
  for (int k=0;k<16;k++){
    int L=(k<<8)|t, rl=L>>6, cl=L&63;
    float v=m67;
    #pragma unroll
    for (int i=0;i<6;i++) v *= sm[i*4+((rl>>(5-i))&1)*2+((cl>>(5-i))&1)];
    slab[physof(L)]=make_float2(v,0.f);
  }
  __syncthreads();
  N1C n2 = noise_coeffs(0.0065f);
  STG(0,0,5) STG(0,1,4) STG(0,2,3) STG(0,3,2) STG(0,4,1)
  STG(1,0,5) STG(1,1,4) STG(1,2,3) STG(1,3,2)
  STG(2,0,5) STG(2,1,4) STG(2,2,3)
  STG(3,0,5) STG(3,1,4)
  STG(4,0,5)
  cplx* g = gout + (size_t)s*65536 + oA*4096;
  #pragma unroll
  for (int k=0;k<16;k++){ int L=(k<<8)|t; g[L]=slab[physof(L)]; }
}

// ---------------- pass B: window qubits 2..7 (bits 0..5), outer = bits 6,7 ----------------
__global__ __launch_bounds__(256) void passB_kernel(const cplx* __restrict__ S1,
                                                    const cplx* __restrict__ gin,
                                                    cplx* __restrict__ gout){
  __shared__ cplx slab[4096];
  __shared__ cplx sS[768];
  int t=threadIdx.x; int s=blockIdx.x>>4, oB=blockIdx.x&15;
  int r67=oB>>2, c67=oB&3;
  for (int i=t;i<768;i+=256) sS[i]=S1[i];
  const cplx* g = gin + (size_t)s*65536;
  #pragma unroll
  for (int mI=0;mI<16;mI++){
    cplx v = g[mI*4096 + (((r67<<4)|(t>>4))<<6) + ((c67<<4)|(t&15))];
    int rlB = ((t>>4)<<2)|(mI>>2);
    int clB = ((t&15)<<2)|(mI&3);
    slab[physof((rlB<<6)|clB)] = v;
  }
  __syncthreads();
  N1C n2 = noise_coeffs(0.0065f);
  STG(0,5,2) STG7(0,6,1)
  STG(1,4,3) STG(1,5,2) STG7(1,6,1)
  STG(2,3,4) STG(2,4,3) STG(2,5,2) STG7(2,6,1)
  STG(3,2,5) STG(3,3,4) STG(3,4,3) STG(3,5,2) STG7(3,6,1)
  cplx* go = gout + (size_t)s*65536 + oB*4096;
  #pragma unroll
  for (int k=0;k<16;k++){ int L=(k<<8)|t; go[L]=slab[physof(L)]; }
}

// ---------------- pass C: window qubits 0..5, reads pass-B layout ----------------
__global__ __launch_bounds__(256) void passC_kernel(const cplx* __restrict__ S1,
                                                    const cplx* __restrict__ gin,
                                                    cplx* __restrict__ gout){
  __shared__ cplx slab[4096];
  __shared__ cplx sS[768];
  int t=threadIdx.x; int s=blockIdx.x>>4, oC=blockIdx.x&15;
  int oCr=oC>>2, oCc=oC&3;
  for (int i=t;i<768;i+=256) sS[i]=S1[i];
  const cplx* g = gin + (size_t)s*65536;
  #pragma unroll
  for (int mI=0;mI<16;mI++){
    int xx=t>>4, y=t&15;
    cplx v = g[mI*4096 + (((xx<<2)|oCr)<<6) + ((y<<2)|oCc)];
    int rlC = ((mI>>2)<<4)|xx;
    int clC = ((mI&3)<<4)|y;
    slab[physof((rlC<<6)|clC)] = v;
  }
  __syncthreads();
  N1C n2 = noise_coeffs(0.0065f);
  STG(4,1,4) STG(4,2,3) STG(4,3,2) STG(4,4,1)
  STG(5,0,5) STG(5,1,4) STG(5,2,3) STG(5,3,2)
  cplx* go = gout + (size_t)s*65536 + oC*4096;
  #pragma unroll
  for (int k=0;k<16;k++){ int L=(k<<8)|t; go[L]=slab[physof(L)]; }
}

// ---------------- pass D: window qubits 2..7, diag outer only, expectation fused ----------------
__global__ __launch_bounds__(256) void passD_kernel(const cplx* __restrict__ S1,
                                                    const cplx* __restrict__ gin,
                                                    float* __restrict__ partial){
  __shared__ cplx slab[4096];
  __shared__ cplx sS[768];
  int t=threadIdx.x; int s=blockIdx.x>>2, dd=blockIdx.x&3;
  int r67=dd, c67=dd;
  for (int i=t;i<768;i+=256) sS[i]=S1[i];
  const cplx* g = gin + (size_t)s*65536;
  #pragma unroll
  for (int mI=0;mI<16;mI++){
    cplx v = g[mI*4096 + (((r67<<4)|(t>>4))<<6) + ((c67<<4)|(t&15))];
    int rlB = ((t>>4)<<2)|(mI>>2);
    int clB = ((t&15)<<2)|(mI&3);
    slab[physof((rlB<<6)|clB)] = v;
  }
  __syncthreads();
  N1C n2 = noise_coeffs(0.0065f);
  STG(4,5,2) STG7(4,6,1)
  STG(5,4,3) STG(5,5,2) STG7(5,6,1)
  if (t < 64){
    float v = slab[physof(t*65)].x;
    #pragma unroll
    for (int o=32;o>0;o>>=1) v += __shfl_down(v,o,64);
    if (t==0) partial[s*4+dd] = (dd&2) ? -v : v;
  }
}

__global__ void final_kernel(const float* __restrict__ partial, float* __restrict__ out){
  int t = threadIdx.x;
  if (t < BATCH) out[t] = partial[4*t]+partial[4*t+1]+partial[4*t+2]+partial[4*t+3];
}

extern "C" void kernel_launch(void* const* d_in, const int* in_sizes, int n_in,
                              void* d_out, int out_size, void* d_ws, size_t ws_size,
                              hipStream_t stream) {
  const float* x = (const float*)d_in[0];   // [32,8]
  const float* w = (const float*)d_in[1];   // [6,8,2]
  float* out = (float*)d_out;               // [32,1] f32
  char* ws = (char*)d_ws;

  cplx*  buf0    = (cplx*)ws;                                   // 16 MB
  cplx*  buf1    = (cplx*)(ws + (size_t)16777216);              // 16 MB
  cplx*  S1      = (cplx*)(ws + (size_t)33554432);              // 6 KB
  float* m       = (float*)(ws + (size_t)33554432 + 6144);      // 4 KB
  float* partial = (float*)(ws + (size_t)33554432 + 6144 + 4096);

  prep_kernel<<<1, 256, 0, stream>>>(x, w, S1, m);
  passA_kernel<<<BATCH*16, 256, 0, stream>>>(S1, m, buf0);
  passB_kernel<<<BATCH*16, 256, 0, stream>>>(S1, buf0, buf1);
  passC_kernel<<<BATCH*16, 256, 0, stream>>>(S1, buf1, buf0);
  passD_kernel<<<BATCH*4, 256, 0, stream>>>(S1, buf0, partial);
  final_kernel<<<1, 64, 0, stream>>>(partial, out);
}